// Round 18
// baseline (363.640 us; speedup 1.0000x reference)
//
#include <hip/hip_runtime.h>

#define FEATN 256
#define XROW  2048      // L*FEAT
#define MT    64        // rows per workgroup
#define LDST  264       // padded LDS row stride (bf16 elems)
#define TILE  (MT * LDST)
#define NSTEP 7

using f32x4  = __attribute__((ext_vector_type(4))) float;
using f32x16 = __attribute__((ext_vector_type(16))) float;
using s16x8  = __attribute__((ext_vector_type(8))) short;

__device__ __forceinline__ short f2bf(float f) {
  unsigned u = __float_as_uint(f);
  u += 0x7fffu + ((u >> 16) & 1u);       // RTNE
  return (short)(u >> 16);
}

__device__ __forceinline__ f32x4 ntload4(const float* p) {
  return __builtin_nontemporal_load(reinterpret_cast<const f32x4*>(p));
}

__device__ __forceinline__ s16x8 pack8(const f32x4 a, const f32x4 b) {
  s16x8 r;
  r[0] = f2bf(a[0]); r[1] = f2bf(a[1]); r[2] = f2bf(a[2]); r[3] = f2bf(a[3]);
  r[4] = f2bf(b[0]); r[5] = f2bf(b[1]); r[6] = f2bf(b[2]); r[7] = f2bf(b[3]);
  return r;
}

// ---------------- weight prep ----------------
// Emits 32x32x16-MFMA B-fragment-layout bf16 weights:
//   B layout: col = lane&31, k = (lane>>5)*8 + j  (within a K=16 step)
//   flat: b*65536 + (n>>5)*8192 + (k>>4)*512 + (((k>>3)&1)*32 + (n&31))*8 + (k&7)
// 0: Wq = Wcs@Wc1   1: Wqc = Wcs@Wc2   2: Wc1   3: Wc2   4: Anti1   5: Anti2
__global__ void prep_kernel(const float* __restrict__ Wc, const float* __restrict__ bc,
                            const float* __restrict__ Wcs, const float* __restrict__ Wanti,
                            short* __restrict__ Wt, float* __restrict__ bq) {
  __shared__ float wrow[FEATN];
  __shared__ float red[FEATN];
  const int n = blockIdx.x, k = threadIdx.x;
  wrow[k] = Wcs[n * FEATN + k];
  __syncthreads();
  float a0 = 0.f, a1 = 0.f;
  #pragma unroll 8
  for (int j = 0; j < FEATN; ++j) {
    const float w = wrow[j];
    a0 += w * Wc[j * 512 + k];
    a1 += w * Wc[j * 512 + 256 + k];
  }
  red[k] = wrow[k] * bc[k];
  __syncthreads();
  for (int off = 128; off > 0; off >>= 1) {
    if (k < off) red[k] += red[k + off];
    __syncthreads();
  }
  if (k == 0) bq[n] = red[0];
  const int fo = (n >> 5) * 8192 + (k >> 4) * 512 + (((k >> 3) & 1) * 32 + (n & 31)) * 8 + (k & 7);
  Wt[0 * 65536 + fo] = f2bf(a0);
  Wt[1 * 65536 + fo] = f2bf(a1);
  Wt[2 * 65536 + fo] = f2bf(Wc[n * 512 + k]);
  Wt[3 * 65536 + fo] = f2bf(Wc[n * 512 + 256 + k]);
  Wt[4 * 65536 + fo] = f2bf(Wanti[n * 512 + k]);
  Wt[5 * 65536 + fo] = f2bf(Wanti[n * 512 + 256 + k]);
}

// ---------------- fused recurrence + output kernel ----------------
// R15 schedule, 32x32x16 MFMA core: 16 waves = 2 row-tiles x 8 col-tiles.
// Halves LDS a-frag reads (48/wave/step) and MFMA instruction count.
__global__ __launch_bounds__(1024, 4)
void chain_kernel(const float* __restrict__ x, const float* __restrict__ endi,
                  const short* __restrict__ Wt, const float* __restrict__ bq,
                  const float* __restrict__ bc, const float* __restrict__ Wout,
                  const float* __restrict__ bout, float* __restrict__ out) {
  __shared__ short sbuf[2 * TILE];               // 67584 B ping-pong bf16 tiles
  __shared__ float redP[MT][9];                  // 2304 B (8 col-tiles + pad)
  __shared__ float selP[MT][17];                 // 4352 B (8*2 + pad)
  __shared__ float cpL[MT], cumL[MT], seL[MT], csL[MT], eiL[MT];   // 1280 B

  const int tid  = (int)threadIdx.x;
  const int lane = tid & 63;
  const int wave = tid >> 6;                     // 0..15
  const int l5   = lane & 31;
  const int h    = lane >> 5;
  const int r0   = (int)blockIdx.x * MT;

  if (tid < MT) { cpL[tid] = 1.f; cumL[tid] = 0.f; seL[tid] = 0.f; }
  for (int i = tid; i < MT * 17; i += 1024) (&selP[0][0])[i] = 0.f;

  // stage x0 into both slots (s0 == x_t at t=0): 8 bf16/thread, 2 iters, b128
  #pragma unroll
  for (int i = 0; i < 2; ++i) {
    const int f = i * 8192 + tid * 8;
    const int row = f >> 8, col = f & 255;
    const float* src = &x[(size_t)(r0 + row) * XROW + col];
    const s16x8 b = pack8(ntload4(src), ntload4(src + 4));
    *reinterpret_cast<s16x8*>(&sbuf[row * LDST + col]) = b;
    *reinterpret_cast<s16x8*>(&sbuf[TILE + row * LDST + col]) = b;
  }

  const int wr  = (wave >> 3) * 32;              // row-tile base
  const int wc  = (wave & 7) * 32;               // col-tile base
  const int wcl = wc + l5;                       // this lane's output col
  const short* wfb = Wt + (wave & 7) * 8192 + lane * 8;   // B-fragment base
  const int abase = (wr + l5) * LDST + h * 8;    // A-frag: row=lane&31, k=(lane>>5)*8+j
  const float bqv = bq[wcl];
  const float bcv = bc[wcl];
  const float wo0 = Wout[256 + wcl];
  const float wo1 = Wout[768 + wcl];

  // s state in registers: sreg[e] = s[row = wr + (e&3)+8*(e>>2)+4*h][col = wcl]
  float sreg[16];
  #pragma unroll
  for (int e = 0; e < 16; ++e) {
    const int row = wr + (e & 3) + 8 * (e >> 2) + 4 * h;
    sreg[e] = x[(size_t)(r0 + row) * XROW + wcl];
  }

  __syncthreads();

  for (int t = 0; t < NSTEP; ++t) {
    const int so = (t & 1) * TILE;               // holds s_t (then x_{t+1})
    const int xo = ((t + 1) & 1) * TILE;         // holds x_t (then s_{t+1})

    // ---- sweep1 (fused): AccA = s@WqT + xt@WqcT ; AccB = s@Wc1T ;
    //      AccN = xt@Anti1T   (each a-frag read once) ----
    f32x16 AccA, AccB, AccN;
    #pragma unroll
    for (int e = 0; e < 16; ++e) { AccA[e] = 0.f; AccB[e] = 0.f; AccN[e] = 0.f; }

    #pragma unroll 1
    for (int ks = 0; ks < 16; ++ks) {
      const short* p = wfb + ks * 512;
      {   // s-operand matrices
        const s16x8 b0 = *reinterpret_cast<const s16x8*>(p + 0 * 65536);
        const s16x8 b2 = *reinterpret_cast<const s16x8*>(p + 2 * 65536);
        const s16x8 a_s = *reinterpret_cast<const s16x8*>(&sbuf[so + abase + ks * 16]);
        AccA = __builtin_amdgcn_mfma_f32_32x32x16_bf16(a_s, b0, AccA, 0, 0, 0);
        AccB = __builtin_amdgcn_mfma_f32_32x32x16_bf16(a_s, b2, AccB, 0, 0, 0);
      }
      {   // x_t-operand matrices
        const s16x8 b1 = *reinterpret_cast<const s16x8*>(p + 1 * 65536);
        const s16x8 b4 = *reinterpret_cast<const s16x8*>(p + 4 * 65536);
        const s16x8 a_x = *reinterpret_cast<const s16x8*>(&sbuf[xo + abase + ks * 16]);
        AccA = __builtin_amdgcn_mfma_f32_32x32x16_bf16(a_x, b1, AccA, 0, 0, 0);
        AccN = __builtin_amdgcn_mfma_f32_32x32x16_bf16(a_x, b4, AccN, 0, 0, 0);
      }
    }
    __syncthreads();   // B1: all s-slot AND x_t-slot reads done

    // ---- stage x_{t+1} into the s-slot (transient b128) ----
    #pragma unroll
    for (int i = 0; i < 2; ++i) {
      const int f = i * 8192 + tid * 8;
      const int row = f >> 8, col = f & 255;
      const float* src = &x[(size_t)(r0 + row) * XROW + (t + 1) * FEATN + col];
      const s16x8 b = pack8(ntload4(src), ntload4(src + 4));
      *reinterpret_cast<s16x8*>(&sbuf[so + row * LDST + col]) = b;
    }
    __syncthreads();   // B2: x_{t+1} visible

    // ---- sweep2 (fused): AccB += x_{t+1}@Wc2T ; AccN += x_{t+1}@Anti2T ----
    #pragma unroll 1
    for (int ks = 0; ks < 16; ++ks) {
      const short* p = wfb + ks * 512;
      const s16x8 b3 = *reinterpret_cast<const s16x8*>(p + 3 * 65536);
      const s16x8 b5 = *reinterpret_cast<const s16x8*>(p + 5 * 65536);
      const s16x8 a_n = *reinterpret_cast<const s16x8*>(&sbuf[so + abase + ks * 16]);
      AccB = __builtin_amdgcn_mfma_f32_32x32x16_bf16(a_n, b3, AccB, 0, 0, 0);
      AccN = __builtin_amdgcn_mfma_f32_32x32x16_bf16(a_n, b5, AccN, 0, 0, 0);
    }

    // ---- dot: sum_d (AccA+bq)*(AccB+bc) -> per-(row,col-tile) into redP ----
    #pragma unroll
    for (int e = 0; e < 16; ++e) {
      float pp = (AccA[e] + bqv) * (AccB[e] + bcv);
      pp += __shfl_xor(pp, 1);
      pp += __shfl_xor(pp, 2);
      pp += __shfl_xor(pp, 4);
      pp += __shfl_xor(pp, 8);
      pp += __shfl_xor(pp, 16);
      if (l5 == 0) redP[wr + (e & 3) + 8 * (e >> 2) + 4 * h][wave & 7] = pp;
    }
    __syncthreads();   // B3: redP visible

    // cs/cumprod bookkeeping (tid<64)
    if (tid < MT) {
      float d = 0.f;
      #pragma unroll
      for (int w = 0; w < 8; ++w) d += redP[tid][w];
      const float cs = 1.f / (1.f + __expf(-d));
      const float cp = cpL[tid] * cs;
      cpL[tid] = cp;
      const float ei = endi[(size_t)(r0 + tid) * 8 + (t + 1)];
      cumL[tid] += cp * ei;
      seL[tid] += ei;
      csL[tid] = cs;
      eiL[tid] = ei;
    }
    __syncthreads();   // B4: csL/eiL visible

    // ---- update: s += tanh(cs*AccN); selP projection; s_{t+1} -> x_t slot ----
    #pragma unroll
    for (int e = 0; e < 16; ++e) {
      const int row = wr + (e & 3) + 8 * (e >> 2) + 4 * h;
      const float cs = csL[row];
      const float ag = cs * AccN[e];
      const float ex = __expf(2.f * ag);
      const float th = 1.f - 2.f / (ex + 1.f);
      const float sn = sreg[e] + th;
      sreg[e] = sn;
      sbuf[xo + row * LDST + wcl] = f2bf(sn);
      if (eiL[row] != 0.f) {                     // uniform across each 32-lane half
        float p0 = sn * wo0;
        float p1 = sn * wo1;
        p0 += __shfl_xor(p0, 1);  p1 += __shfl_xor(p1, 1);
        p0 += __shfl_xor(p0, 2);  p1 += __shfl_xor(p1, 2);
        p0 += __shfl_xor(p0, 4);  p1 += __shfl_xor(p1, 4);
        p0 += __shfl_xor(p0, 8);  p1 += __shfl_xor(p1, 8);
        p0 += __shfl_xor(p0, 16); p1 += __shfl_xor(p1, 16);
        if (l5 == 0) { selP[row][(wave & 7) * 2] = p0; selP[row][(wave & 7) * 2 + 1] = p1; }
      }
    }
    __syncthreads();   // B5: s_{t+1} visible for next sweep1
  }

  // final: one group of 8 rows per wave (waves 0..7), softmax over cum, combine
  if (wave < 8) {
    const int g = wave;
    const int rowb = g * 8;
    float c[8];
    float mx = -3.4e38f;
    #pragma unroll
    for (int m = 0; m < 8; ++m) {
      c[m] = cumL[rowb + m] - (1.f - seL[rowb + m]) * 10000.f;
      mx = fmaxf(mx, c[m]);
    }
    float sum = 0.f;
    float wgt[8];
    #pragma unroll
    for (int m = 0; m < 8; ++m) { wgt[m] = __expf(c[m] - mx); sum += wgt[m]; }
    const float inv = 1.f / sum;
    float up0 = 0.f, up1 = 0.f;
    #pragma unroll
    for (int m = 0; m < 8; ++m) {
      float s0 = 0.f, s1 = 0.f;
      #pragma unroll
      for (int w = 0; w < 8; ++w) {
        s0 += selP[rowb + m][w * 2];
        s1 += selP[rowb + m][w * 2 + 1];
      }
      const float wm = wgt[m] * inv;
      up0 += wm * s0; up1 += wm * s1;
    }
    const int d = lane * 4;
    const float4 xv  = *reinterpret_cast<const float4*>(&x[(size_t)(r0 + rowb) * XROW + d]);
    const float4 w00 = *reinterpret_cast<const float4*>(&Wout[d]);
    const float4 w10 = *reinterpret_cast<const float4*>(&Wout[512 + d]);
    float o0 = xv.x * w00.x + xv.y * w00.y + xv.z * w00.z + xv.w * w00.w;
    float o1 = xv.x * w10.x + xv.y * w10.y + xv.z * w10.z + xv.w * w10.w;
    #pragma unroll
    for (int off = 1; off < 64; off <<= 1) {
      o0 += __shfl_xor(o0, off);
      o1 += __shfl_xor(o1, off);
    }
    if (lane == 0) {
      const int n = (int)blockIdx.x * 8 + g;
      out[n * 2 + 0] = o0 + up0 + bout[0];
      out[n * 2 + 1] = o1 + up1 + bout[1];
    }
  }
}

extern "C" void kernel_launch(void* const* d_in, const int* in_sizes, int n_in,
                              void* d_out, int out_size, void* d_ws, size_t ws_size,
                              hipStream_t stream) {
  const float* x     = (const float*)d_in[0];
  const float* endi  = (const float*)d_in[1];
  // d_in[2] = max_chain (==8, hard-coded)
  const float* Wc    = (const float*)d_in[3];
  const float* bc    = (const float*)d_in[4];
  const float* Wcs   = (const float*)d_in[5];
  const float* Wanti = (const float*)d_in[6];
  const float* Wout  = (const float*)d_in[7];
  const float* bout  = (const float*)d_in[8];
  float* out = (float*)d_out;

  char* ws = (char*)d_ws;
  short* Wt = (short*)ws;                 // 6*256*256*2 = 768 KB (fragment layout)
  float* bq = (float*)(ws + 786432);      // 1 KB

  prep_kernel<<<dim3(256), dim3(256), 0, stream>>>(Wc, bc, Wcs, Wanti, Wt, bq);
  chain_kernel<<<dim3(512), dim3(1024), 0, stream>>>(x, endi, Wt, bq, bc, Wout, bout, out);
}

// Round 19
// 257.381 us; speedup vs baseline: 1.4128x; 1.4128x over previous
//
#include <hip/hip_runtime.h>
#include <hip/hip_bf16.h>

#define FEATN 256
#define XROW  2048      // L*FEAT
#define MT    64        // rows per workgroup
#define NW    16        // waves per workgroup (each owns 16 output cols)
#define LDST  264       // padded LDS row stride (bf16 elems)
#define TILE  (MT * LDST)
#define NSTEP 7

using f32x4 = __attribute__((ext_vector_type(4))) float;
using s16x8 = __attribute__((ext_vector_type(8))) short;

__device__ __forceinline__ short f2bf(float f) {
  __hip_bfloat16 h = __float2bfloat16(f);     // RTNE; compiler emits v_cvt_pk_bf16_f32 for pairs
  return *reinterpret_cast<short*>(&h);
}

__device__ __forceinline__ f32x4 ntload4(const float* p) {
  return __builtin_nontemporal_load(reinterpret_cast<const f32x4*>(p));
}

__device__ __forceinline__ s16x8 pack8(const f32x4 a, const f32x4 b) {
  s16x8 r;
  r[0] = f2bf(a[0]); r[1] = f2bf(a[1]); r[2] = f2bf(a[2]); r[3] = f2bf(a[3]);
  r[4] = f2bf(b[0]); r[5] = f2bf(b[1]); r[6] = f2bf(b[2]); r[7] = f2bf(b[3]);
  return r;
}

// 16-lane butterfly reduce via DPP (VALU-only; no LDS-pipe traffic).
// Valid because each lr-group (lanes lh*16 .. lh*16+15) is a DPP row.
__device__ __forceinline__ float dpp_red16(float x) {
  x += __int_as_float(__builtin_amdgcn_update_dpp(0, __float_as_int(x), 0xB1, 0xF, 0xF, true));  // xor 1
  x += __int_as_float(__builtin_amdgcn_update_dpp(0, __float_as_int(x), 0x4E, 0xF, 0xF, true));  // xor 2
  x += __int_as_float(__builtin_amdgcn_update_dpp(0, __float_as_int(x), 0x141, 0xF, 0xF, true)); // xor 4 (half-mirror)
  x += __int_as_float(__builtin_amdgcn_update_dpp(0, __float_as_int(x), 0x140, 0xF, 0xF, true)); // xor 8 (mirror)
  return x;
}

// ---------------- weight prep ----------------
// Emits MFMA-B-fragment-layout bf16 weights:
//   flat: b*65536 + (n>>4)*4096 + (k>>5)*512 + (((k>>3)&3)*16 + (n&15))*8 + (k&7)
// 0: Wq = Wcs@Wc1   1: Wqc = Wcs@Wc2   2: Wc1   3: Wc2   4: Anti1   5: Anti2
__global__ void prep_kernel(const float* __restrict__ Wc, const float* __restrict__ bc,
                            const float* __restrict__ Wcs, const float* __restrict__ Wanti,
                            short* __restrict__ Wt, float* __restrict__ bq) {
  __shared__ float wrow[FEATN];
  __shared__ float red[FEATN];
  const int n = blockIdx.x, k = threadIdx.x;
  wrow[k] = Wcs[n * FEATN + k];
  __syncthreads();
  float a0 = 0.f, a1 = 0.f;
  #pragma unroll 8
  for (int j = 0; j < FEATN; ++j) {
    const float w = wrow[j];
    a0 += w * Wc[j * 512 + k];
    a1 += w * Wc[j * 512 + 256 + k];
  }
  red[k] = wrow[k] * bc[k];
  __syncthreads();
  for (int off = 128; off > 0; off >>= 1) {
    if (k < off) red[k] += red[k + off];
    __syncthreads();
  }
  if (k == 0) bq[n] = red[0];
  const int fo = (n >> 4) * 4096 + (k >> 5) * 512 + (((k >> 3) & 3) * 16 + (n & 15)) * 8 + (k & 7);
  Wt[0 * 65536 + fo] = f2bf(a0);
  Wt[1 * 65536 + fo] = f2bf(a1);
  Wt[2 * 65536 + fo] = f2bf(Wc[n * 512 + k]);
  Wt[3 * 65536 + fo] = f2bf(Wc[n * 512 + 256 + k]);
  Wt[4 * 65536 + fo] = f2bf(Wanti[n * 512 + k]);
  Wt[5 * 65536 + fo] = f2bf(Wanti[n * 512 + 256 + k]);
}

// ---------------- fused recurrence + output kernel ----------------
// R15 structure; shfl trees -> DPP butterflies; bf16 converts -> cvt_pk path.
__global__ __launch_bounds__(1024, 4)
void chain_kernel(const float* __restrict__ x, const float* __restrict__ endi,
                  const short* __restrict__ Wt, const float* __restrict__ bq,
                  const float* __restrict__ bc, const float* __restrict__ Wout,
                  const float* __restrict__ bout, float* __restrict__ out) {
  __shared__ short sbuf[2 * TILE];               // 67584 B ping-pong bf16 tiles
  __shared__ float redP[MT][NW];                 // 4096 B
  __shared__ float selP[MT][2 * NW];             // 8192 B
  __shared__ float cpL[MT], cumL[MT], seL[MT], csL[MT], eiL[MT];   // 1280 B

  const int tid  = (int)threadIdx.x;
  const int lane = tid & 63;
  const int wave = tid >> 6;                     // 0..15
  const int lr   = lane & 15;
  const int lh   = lane >> 4;
  const int r0   = (int)blockIdx.x * MT;

  if (tid < MT) { cpL[tid] = 1.f; cumL[tid] = 0.f; seL[tid] = 0.f; }
  #pragma unroll
  for (int i = 0; i < 2; ++i) (&selP[0][0])[i * 1024 + tid] = 0.f;

  // stage x0 into both slots (s0 == x_t at t=0): 8 bf16/thread, 2 iters, b128
  #pragma unroll
  for (int i = 0; i < 2; ++i) {
    const int f = i * 8192 + tid * 8;
    const int row = f >> 8, col = f & 255;
    const float* src = &x[(size_t)(r0 + row) * XROW + col];
    const s16x8 b = pack8(ntload4(src), ntload4(src + 4));
    *reinterpret_cast<s16x8*>(&sbuf[row * LDST + col]) = b;
    *reinterpret_cast<s16x8*>(&sbuf[TILE + row * LDST + col]) = b;
  }

  const int wcol = wave * 16 + lr;               // this wave's output col
  const short* wfb = Wt + wave * 4096 + lane * 8;   // fragment-layout base
  const int abase = lr * LDST + lh * 8;
  const float bqv = bq[wcol];
  const float bcv = bc[wcol];
  const float wo0 = Wout[256 + wcol];
  const float wo1 = Wout[768 + wcol];
  const f32x4 fzero = {0.f, 0.f, 0.f, 0.f};

  // s state in registers: sreg[m][e] = s[row = m*16+lh*4+e][col = wcol]
  float sreg[4][4];
  #pragma unroll
  for (int m = 0; m < 4; ++m)
    #pragma unroll
    for (int e = 0; e < 4; ++e)
      sreg[m][e] = x[(size_t)(r0 + m * 16 + lh * 4 + e) * XROW + wcol];

  __syncthreads();

  for (int t = 0; t < NSTEP; ++t) {
    const int so = (t & 1) * TILE;               // holds s_t (then x_{t+1})
    const int xo = ((t + 1) & 1) * TILE;         // holds x_t (then s_{t+1})

    // ---- sweep1 (fused): AccA = s@WqT + xt@WqcT ; AccB = s@Wc1T ;
    //      AccN = xt@Anti1T   (each a-frag read once) ----
    f32x4 AccA[4], AccB[4], AccN[4];
    #pragma unroll
    for (int m = 0; m < 4; ++m) { AccA[m] = fzero; AccB[m] = fzero; AccN[m] = fzero; }

    #pragma unroll 1
    for (int ks = 0; ks < 8; ++ks) {
      const short* p = wfb + ks * 512;
      {   // sub-phase A: s-operand matrices
        const s16x8 b0 = *reinterpret_cast<const s16x8*>(p + 0 * 65536);
        const s16x8 b2 = *reinterpret_cast<const s16x8*>(p + 2 * 65536);
        #pragma unroll
        for (int m = 0; m < 4; ++m) {
          const s16x8 a_s = *reinterpret_cast<const s16x8*>(&sbuf[so + abase + m * (16 * LDST) + ks * 32]);
          AccA[m] = __builtin_amdgcn_mfma_f32_16x16x32_bf16(a_s, b0, AccA[m], 0, 0, 0);
          AccB[m] = __builtin_amdgcn_mfma_f32_16x16x32_bf16(a_s, b2, AccB[m], 0, 0, 0);
        }
      }
      {   // sub-phase B: x_t-operand matrices
        const s16x8 b1 = *reinterpret_cast<const s16x8*>(p + 1 * 65536);
        const s16x8 b4 = *reinterpret_cast<const s16x8*>(p + 4 * 65536);
        #pragma unroll
        for (int m = 0; m < 4; ++m) {
          const s16x8 a_x = *reinterpret_cast<const s16x8*>(&sbuf[xo + abase + m * (16 * LDST) + ks * 32]);
          AccA[m] = __builtin_amdgcn_mfma_f32_16x16x32_bf16(a_x, b1, AccA[m], 0, 0, 0);
          AccN[m] = __builtin_amdgcn_mfma_f32_16x16x32_bf16(a_x, b4, AccN[m], 0, 0, 0);
        }
      }
    }
    __syncthreads();   // B1: all s-slot AND x_t-slot reads done

    // ---- stage x_{t+1} into the s-slot (transient b128) ----
    #pragma unroll
    for (int i = 0; i < 2; ++i) {
      const int f = i * 8192 + tid * 8;
      const int row = f >> 8, col = f & 255;
      const float* src = &x[(size_t)(r0 + row) * XROW + (t + 1) * FEATN + col];
      const s16x8 b = pack8(ntload4(src), ntload4(src + 4));
      *reinterpret_cast<s16x8*>(&sbuf[so + row * LDST + col]) = b;
    }
    __syncthreads();   // B2: x_{t+1} visible

    // ---- sweep2 (fused): AccB += x_{t+1}@Wc2T ; AccN += x_{t+1}@Anti2T ----
    #pragma unroll 1
    for (int ks = 0; ks < 8; ++ks) {
      const short* p = wfb + ks * 512;
      const s16x8 b3 = *reinterpret_cast<const s16x8*>(p + 3 * 65536);
      const s16x8 b5 = *reinterpret_cast<const s16x8*>(p + 5 * 65536);
      #pragma unroll
      for (int m = 0; m < 4; ++m) {
        const s16x8 a_n = *reinterpret_cast<const s16x8*>(&sbuf[so + abase + m * (16 * LDST) + ks * 32]);
        AccB[m] = __builtin_amdgcn_mfma_f32_16x16x32_bf16(a_n, b3, AccB[m], 0, 0, 0);
        AccN[m] = __builtin_amdgcn_mfma_f32_16x16x32_bf16(a_n, b5, AccN[m], 0, 0, 0);
      }
    }

    // ---- dot: sum_d (AccA+bq)*(AccB+bc) via DPP butterfly ----
    #pragma unroll
    for (int m = 0; m < 4; ++m) {
      #pragma unroll
      for (int e = 0; e < 4; ++e) {
        const float p = dpp_red16((AccA[m][e] + bqv) * (AccB[m][e] + bcv));
        if (lr == 0) redP[m * 16 + lh * 4 + e][wave] = p;
      }
    }
    __syncthreads();   // B3: redP visible

    // cs/cumprod bookkeeping (tid<64)
    if (tid < MT) {
      float d = 0.f;
      #pragma unroll
      for (int w = 0; w < NW; ++w) d += redP[tid][w];
      const float cs = 1.f / (1.f + __expf(-d));
      const float cp = cpL[tid] * cs;
      cpL[tid] = cp;
      const float ei = endi[(size_t)(r0 + tid) * 8 + (t + 1)];
      cumL[tid] += cp * ei;
      seL[tid] += ei;
      csL[tid] = cs;
      eiL[tid] = ei;
    }
    __syncthreads();   // B4: csL/eiL visible

    // ---- update: s += tanh(cs*AccN); selP projection; s_{t+1} -> x_t slot ----
    #pragma unroll
    for (int m = 0; m < 4; ++m) {
      #pragma unroll
      for (int e = 0; e < 4; ++e) {
        const int row = m * 16 + lh * 4 + e;
        const float cs = csL[row];
        const float ag = cs * AccN[m][e];
        const float ex = __expf(2.f * ag);
        const float th = 1.f - 2.f / (ex + 1.f);
        const float sn = sreg[m][e] + th;
        sreg[m][e] = sn;
        sbuf[xo + row * LDST + wcol] = f2bf(sn);
        if (eiL[row] != 0.f) {                   // uniform across the lr group
          const float p0 = dpp_red16(sn * wo0);
          const float p1 = dpp_red16(sn * wo1);
          if (lr == 0) { selP[row][wave * 2] = p0; selP[row][wave * 2 + 1] = p1; }
        }
      }
    }
    __syncthreads();   // B5: s_{t+1} visible for next sweep1
  }

  // final: one group of 8 rows per wave (waves 0..7), softmax over cum, combine
  if (wave < 8) {
    const int g = wave;
    const int rowb = g * 8;
    float c[8];
    float mx = -3.4e38f;
    #pragma unroll
    for (int m = 0; m < 8; ++m) {
      c[m] = cumL[rowb + m] - (1.f - seL[rowb + m]) * 10000.f;
      mx = fmaxf(mx, c[m]);
    }
    float sum = 0.f;
    float wgt[8];
    #pragma unroll
    for (int m = 0; m < 8; ++m) { wgt[m] = __expf(c[m] - mx); sum += wgt[m]; }
    const float inv = 1.f / sum;
    float up0 = 0.f, up1 = 0.f;
    #pragma unroll
    for (int m = 0; m < 8; ++m) {
      float s0 = 0.f, s1 = 0.f;
      #pragma unroll
      for (int w = 0; w < NW; ++w) {
        s0 += selP[rowb + m][w * 2];
        s1 += selP[rowb + m][w * 2 + 1];
      }
      const float wm = wgt[m] * inv;
      up0 += wm * s0; up1 += wm * s1;
    }
    const int d = lane * 4;
    const float4 xv  = *reinterpret_cast<const float4*>(&x[(size_t)(r0 + rowb) * XROW + d]);
    const float4 w00 = *reinterpret_cast<const float4*>(&Wout[d]);
    const float4 w10 = *reinterpret_cast<const float4*>(&Wout[512 + d]);
    float o0 = xv.x * w00.x + xv.y * w00.y + xv.z * w00.z + xv.w * w00.w;
    float o1 = xv.x * w10.x + xv.y * w10.y + xv.z * w10.z + xv.w * w10.w;
    #pragma unroll
    for (int off = 1; off < 64; off <<= 1) {
      o0 += __shfl_xor(o0, off);
      o1 += __shfl_xor(o1, off);
    }
    if (lane == 0) {
      const int n = (int)blockIdx.x * 8 + g;
      out[n * 2 + 0] = o0 + up0 + bout[0];
      out[n * 2 + 1] = o1 + up1 + bout[1];
    }
  }
}

extern "C" void kernel_launch(void* const* d_in, const int* in_sizes, int n_in,
                              void* d_out, int out_size, void* d_ws, size_t ws_size,
                              hipStream_t stream) {
  const float* x     = (const float*)d_in[0];
  const float* endi  = (const float*)d_in[1];
  // d_in[2] = max_chain (==8, hard-coded)
  const float* Wc    = (const float*)d_in[3];
  const float* bc    = (const float*)d_in[4];
  const float* Wcs   = (const float*)d_in[5];
  const float* Wanti = (const float*)d_in[6];
  const float* Wout  = (const float*)d_in[7];
  const float* bout  = (const float*)d_in[8];
  float* out = (float*)d_out;

  char* ws = (char*)d_ws;
  short* Wt = (short*)ws;                 // 6*256*256*2 = 768 KB (fragment layout)
  float* bq = (float*)(ws + 786432);      // 1 KB

  prep_kernel<<<dim3(256), dim3(256), 0, stream>>>(Wc, bc, Wcs, Wanti, Wt, bq);
  chain_kernel<<<dim3(512), dim3(1024), 0, stream>>>(x, endi, Wt, bq, bc, Wout, bout, out);
}